// Round 11
// baseline (6683.932 us; speedup 1.0000x reference)
//
#include <hip/hip_runtime.h>

// ---------------------------------------------------------------------------
// 2-layer ReLU RNN, B=64 T=2048 IN=256 H=512 C=128. fp32 inputs (runtime
// dtype detect kept), output dtype matches input.
//
// Round-16: round-15 (direct col-major publish, single-barrier-ish step,
// 6043us scan) + two coupled changes to the latency-bound sibling exchange:
//  (1) 256-col recurrent WGs (2 siblings/row-group, was 4): W = 128 cols in
//      registers (4 waves x Bf[2][16] = 128 VGPR, proven) + 128 cols in LDS
//      WL (128KB, filled once -- r12 mechanism, sound; r12's failure was
//      VGPR overflow which is absent here). LDS 16KB stage + 128KB WL =
//      144KB (proven launchable); PROJ's sH0 aliases WL.
//  (2) K-split MFMA around the exchange: K=512 = own-half (cols this WG
//      computed -- in LDS immediately) + remote-half. Schedule per step:
//      B1 -> D1 MFMA own-K (covers remote flight) -> validate+scatter
//      remote -> B2 -> D2 MFMA remote-K -> E relu/publish/issue-loads.
//      Static unroll preserved by branching on uniform s (rule: runtime
//      array indices spill to scratch).
// Flow control: hex0 8-ring sign tags (h>=0), hexZ 8-ring LSB tags (z
// signed), hex1 2-ring; LAG=7; progP[r*4+q] gates L0's hex0 reuse;
// progL[r*2+s] gates PROJ(q)'s hexZ reuse (consuming half s=q>>1).
// All spins guard-limited -> no hangs (worst case wrong data -> absmax).
// Grid = 32 x 256: b<16: s=b>>3, c=b&7 -> role=c>>2 (0=L0,1=L1REC), r=c&3
// (sibling pair b, b+8 -> same XCD under round-robin). b>=16: PROJ
// r=(b-16)>>2, q=(b-16)&3 (128 cols, r15-verbatim).
// ---------------------------------------------------------------------------

typedef unsigned short u16;
typedef unsigned int u32;
typedef unsigned long long u64;
typedef _Float16 f16;
typedef _Float16 half8 __attribute__((ext_vector_type(8)));
typedef float float4v __attribute__((ext_vector_type(4)));

#define T_LEN 2048
#define H_DIM 512
#define B_SZ 64
#define SGN 0x8000800080008000ull
#define VMASK 0x7fff7fff7fff7fffull
#define ZMASK 0x0001000100010001ull
#define SPIN_LIM (1 << 15)
#define LAG 7

__device__ __forceinline__ float bf2f(u16 u) {
    union { u32 i; float f; } v; v.i = ((u32)u) << 16; return v.f;
}
__device__ __forceinline__ u16 f2bf(float f) {
    u32 x = __float_as_uint(f);
    u32 r = (x + 0x7fffu + ((x >> 16) & 1u)) >> 16;
    return (u16)r;
}
__device__ __forceinline__ float loadf(const void* p, size_t i, int dt) {
    return dt ? ((const float*)p)[i] : bf2f(((const u16*)p)[i]);
}
__device__ __forceinline__ half8 cvt8_bf16(uint4 v) {
    half8 h;
    h[0] = (f16)bf2f((u16)(v.x & 0xffff)); h[1] = (f16)bf2f((u16)(v.x >> 16));
    h[2] = (f16)bf2f((u16)(v.y & 0xffff)); h[3] = (f16)bf2f((u16)(v.y >> 16));
    h[4] = (f16)bf2f((u16)(v.z & 0xffff)); h[5] = (f16)bf2f((u16)(v.z >> 16));
    h[6] = (f16)bf2f((u16)(v.w & 0xffff)); h[7] = (f16)bf2f((u16)(v.w >> 16));
    return h;
}
__device__ __forceinline__ u64 tagmask(int t) {   // sign-bit tag (h >= 0)
    return ((t & 1) ? 0x0000000000008000ull : 0ull) |
           ((t & 2) ? 0x0000000080000000ull : 0ull) |
           ((t & 4) ? 0x0000800000000000ull : 0ull) |
           ((t & 8) ? 0x8000000000000000ull : 0ull);
}
__device__ __forceinline__ u64 ztag(int t) {      // LSB tag (z signed)
    return ((u64)(t & 1)) | ((u64)((t >> 1) & 1) << 16) |
           ((u64)((t >> 2) & 1) << 32) | ((u64)((t >> 3) & 1) << 48);
}
__device__ __forceinline__ u64 aload(u64* p) {
    return __hip_atomic_load(p, __ATOMIC_RELAXED, __HIP_MEMORY_SCOPE_AGENT);
}
__device__ __forceinline__ void astore(u64* p, u64 v) {
    __hip_atomic_store(p, v, __ATOMIC_RELAXED, __HIP_MEMORY_SCOPE_AGENT);
}
__device__ __forceinline__ u32 aload32(u32* p) {
    return __hip_atomic_load(p, __ATOMIC_RELAXED, __HIP_MEMORY_SCOPE_AGENT);
}
__device__ __forceinline__ void astore32(u32* p, u32 v) {
    __hip_atomic_store(p, v, __ATOMIC_RELAXED, __HIP_MEMORY_SCOPE_AGENT);
}
__device__ __forceinline__ float f16u(u16 b) {
    union { u16 u; f16 h; } c; c.u = b; return (float)c.h;
}
// Scatter one col-major u64 (word = col*4 + quad) into swizzled stage.
__device__ __forceinline__ void scat_store(f16* sbuf, int word, u64 v) {
    int col = word >> 2, q = word & 3;
#pragma unroll
    for (int i = 0; i < 4; ++i) {
        int row = q * 4 + i;
        union { u16 u; f16 h; } c;
        c.u = (u16)(v >> (16 * i));
        sbuf[row * 512 + ((col >> 3) ^ (row & 7)) * 8 + (col & 7)] = c.h;
    }
}

// --------------------------- dtype detection -------------------------------
__global__ void detect_kernel(const u16* __restrict__ xr, int* __restrict__ dtf,
                              u32* __restrict__ progP, u32* __restrict__ progL) {
    int lane = threadIdx.x;
    u16 u0 = xr[(lane * 2 + 0) * 2];
    u16 u1 = xr[(lane * 2 + 1) * 2];
    int e0 = (u0 >> 7) & 0xff, e1 = (u1 >> 7) & 0xff;
    int c0 = (e0 >= 0x60 && e0 <= 0x8f) ? 1 : 0;
    int c1 = (e1 >= 0x60 && e1 <= 0x8f) ? 1 : 0;
    int tot = __popcll(__ballot(c0)) + __popcll(__ballot(c1));
    if (lane == 0) *dtf = (tot >= 96) ? 0 : 1;   // 0 = bf16, 1 = fp32
    progP[lane] = 0;
    progL[lane] = 0;
}

// --------------------------- prep kernels ----------------------------------
__global__ void cvt_w_kernel(const void* __restrict__ in, f16* __restrict__ out,
                             int n, const int* __restrict__ dtf) {
    int dt = *dtf;
    for (int i = blockIdx.x * blockDim.x + threadIdx.x; i < n; i += gridDim.x * blockDim.x)
        out[i] = (f16)loadf(in, i, dt);
}

__global__ void bias_kernel(const void* __restrict__ bi, const void* __restrict__ bh,
                            float* __restrict__ bias, const int* __restrict__ dtf) {
    int dt = *dtf;
    int i = blockIdx.x * blockDim.x + threadIdx.x;
    if (i < H_DIM) bias[i] = loadf(bi, i, dt) + loadf(bh, i, dt);
}

__global__ void fcb_kernel(const void* __restrict__ in, float* __restrict__ out,
                           const int* __restrict__ dtf) {
    int i = threadIdx.x;
    if (i < 128) out[i] = loadf(in, i, *dtf);
}

__global__ void initz_kernel(u64* __restrict__ hexZ) {
    int i = blockIdx.x * blockDim.x + threadIdx.x;   // 65536 threads
    hexZ[i] = 0x0001000100010001ull;                 // LSB tag 15
}

// --------------------------- tiled MFMA GEMM -------------------------------
template<int RAW>
__global__ __launch_bounds__(256)
void gemm_tiled(const void* __restrict__ Araw, const f16* __restrict__ Bw,
                const float* __restrict__ bias, f16* __restrict__ C,
                int lgTc, int t_off, int K, const int* __restrict__ dtf)
{
    __shared__ f16 As[64][40];
    __shared__ f16 Bs[64][40];
    const int dt = RAW ? *dtf : 0;
    const int m0 = blockIdx.x * 64, n0 = blockIdx.y * 64;
    const int tid = threadIdx.x;
    const int wv = tid >> 6, lane = tid & 63;
    const int lr = lane & 15, quad = lane >> 4;
    const int srow = tid >> 2, skq = tid & 3;

    float4v acc[4] = {{0.f,0.f,0.f,0.f},{0.f,0.f,0.f,0.f},{0.f,0.f,0.f,0.f},{0.f,0.f,0.f,0.f}};

    size_t arow;
    {
        int ml = m0 + srow;
        if (RAW) {
            int b = ml >> lgTc, tt = ml & ((1 << lgTc) - 1);
            arow = (size_t)b * T_LEN + t_off + tt;
        } else arow = (size_t)ml;
    }
    const f16* pb = Bw + (size_t)(n0 + srow) * K + skq * 8;

    for (int k0 = 0; k0 < K; k0 += 32) {
        half8 av;
        if (RAW) {
            if (dt) {
                const float* ap = (const float*)Araw + arow * K + k0 + skq * 8;
                float4v f0 = *(const float4v*)ap;
                float4v f1 = *(const float4v*)(ap + 4);
                av[0]=(f16)f0[0]; av[1]=(f16)f0[1]; av[2]=(f16)f0[2]; av[3]=(f16)f0[3];
                av[4]=(f16)f1[0]; av[5]=(f16)f1[1]; av[6]=(f16)f1[2]; av[7]=(f16)f1[3];
            } else {
                av = cvt8_bf16(*(const uint4*)((const u16*)Araw + arow * K + k0 + skq * 8));
            }
        } else {
            av = *(const half8*)((const f16*)Araw + arow * K + k0 + skq * 8);
        }
        half8 bv = *(const half8*)(pb + k0);
        __syncthreads();
        *(half8*)&As[srow][skq * 8] = av;
        *(half8*)&Bs[srow][skq * 8] = bv;
        __syncthreads();
        half8 bf = *(const half8*)&Bs[wv * 16 + lr][quad * 8];
#pragma unroll
        for (int mt = 0; mt < 4; ++mt) {
            half8 af = *(const half8*)&As[mt * 16 + lr][quad * 8];
            acc[mt] = __builtin_amdgcn_mfma_f32_16x16x32_f16(af, bf, acc[mt], 0, 0, 0);
        }
    }
    const int n = n0 + wv * 16 + lr;
    const float bval = bias[n];
#pragma unroll
    for (int mt = 0; mt < 4; ++mt) {
#pragma unroll
        for (int i = 0; i < 4; ++i) {
            int m = m0 + mt * 16 + quad * 4 + i;
            C[(size_t)m * H_DIM + n] = (f16)(acc[mt][i] + bval);
        }
    }
}

// --------------------------- 3-role scan -----------------------------------
// grid = 32 x 256 (4 waves, 1 wave/SIMD). LDS 144KB -> 1 WG/CU.
// hex0 [8][4][2048] u64 col-major (sign tags), hex1 [2][4][2048],
// hexZ [8][4][2048] (LSB tags). word = col*4 + quad; u64 = rows q*4..+3.
__global__ __launch_bounds__(256, 1)
void rnn_scan3(const f16* __restrict__ pre0,    // [B,Tc,H] chunk-local
               const f16* __restrict__ Whh0,    // [H,H] fp16
               const f16* __restrict__ Wih1,    // [H,H] fp16
               const f16* __restrict__ Whh1,    // [H,H] fp16
               const float* __restrict__ bias1, // [H] fp32
               u64* __restrict__ hex0,          // [8][4][2048]
               u64* __restrict__ hex1,          // [2][4][2048]
               u64* __restrict__ hexZ,          // [8][4][2048]
               f16* __restrict__ hc0,           // [B,H] layer-0 carry
               f16* __restrict__ hc1,           // [B,H] layer-1 carry
               u32* __restrict__ progP,         // [16 used]
               u32* __restrict__ progL,         // [8 used]
               int t0, int Tc,
               float* __restrict__ h_last)      // [B,H] fp32
{
    __shared__ f16 stage[16 * 512];    // 16KB: h (rec) -- full 512 cols
    __shared__ f16 big[128 * 512];     // 128KB: WL (rec) / sH0 alias (PROJ)
    const int b = blockIdx.x;
    const int tid = threadIdx.x;
    const int w = tid >> 6, lane = tid & 63;
    const int lr = lane & 15, quad = lane >> 4;

    if (b >= 16) {
        // ============================ PROJ (r15-verbatim) ============================
        const int pr = b - 16;
        const int r = pr >> 2, q = pr & 3;
        f16* sH0 = big;                       // 16KB of the 128KB block
        const int c0p = q * 128 + w * 32;
        half8 Bp[2][16];
#pragma unroll
        for (int j = 0; j < 2; ++j)
#pragma unroll
            for (int kc = 0; kc < 16; ++kc)
                Bp[j][kc] = *(const half8*)(Wih1 + (size_t)(c0p + j * 16 + lr) * H_DIM
                                            + kc * 32 + quad * 8);
        float bvv[2] = { bias1[c0p + lr], bias1[c0p + 16 + lr] };
        const int z0 = (c0p + lr) * 4 + quad;
        const int wbase = tid * 8;
        const int sgate = r * 2 + (q >> 1);   // consuming L1REC half

        u64 vv[8];
        {
            u64* src = hex0 + ((size_t)(t0 & 7) * 4 + r) * 2048;
#pragma unroll
            for (int k = 0; k < 8; ++k) vv[k] = aload(&src[wbase + k]);
        }

        for (int tt = 0; tt < Tc; ++tt) {
            const int t = t0 + tt;
            const int nb = t & 7;
            const u64 em = tagmask(t);
            const int need = t - LAG;
            const u32 want = (u32)(need + 1);

            u32 plv = 0xffffffffu;
            if (need >= 0) plv = aload32(&progL[sgate]);   // early poll

            // [A] validate h0_t (all 8 words) -> sH0
            {
                u64* src = hex0 + ((size_t)nb * 4 + r) * 2048;
                int pend = 0;
#pragma unroll
                for (int k = 0; k < 8; ++k)
                    if ((vv[k] & SGN) != em) pend |= 1 << k;
                int guard = 0;
                while (pend && guard < SPIN_LIM) {
#pragma unroll
                    for (int k = 0; k < 8; ++k)
                        if (pend & (1 << k)) vv[k] = aload(&src[wbase + k]);
#pragma unroll
                    for (int k = 0; k < 8; ++k)
                        if ((pend & (1 << k)) && ((vv[k] & SGN) == em))
                            pend &= ~(1 << k);
                    ++guard;
                }
#pragma unroll
                for (int k = 0; k < 8; ++k)
                    scat_store(sH0, wbase + k, vv[k] & VMASK);
            }
            __syncthreads();   // sH0 ready; all hex0[t] reads done
            if (tid == 0) astore32(&progP[r * 4 + q], (u32)(t + 1));

            float4v acc0 = {0.f,0.f,0.f,0.f}, acc1 = {0.f,0.f,0.f,0.f};
#pragma unroll
            for (int kc = 0; kc < 16; ++kc) {
                half8 a = *(const half8*)&sH0[lr * 512 + (((kc * 4 + quad) ^ (lr & 7)) * 8)];
                acc0 = __builtin_amdgcn_mfma_f32_16x16x32_f16(a, Bp[0][kc], acc0, 0, 0, 0);
                acc1 = __builtin_amdgcn_mfma_f32_16x16x32_f16(a, Bp[1][kc], acc1, 0, 0, 0);
            }

            // pack z with LSB tags
            const u64 ez = ztag(t);
            u64 zw[2];
#pragma unroll
            for (int j = 0; j < 2; ++j) {
                const float4v& a = j ? acc1 : acc0;
                u64 wp = 0;
#pragma unroll
                for (int i = 0; i < 4; ++i) {
                    union { f16 h; u16 u; } c;
                    c.h = (f16)(a[i] + bvv[j]);
                    wp |= ((u64)(c.u & 0xFFFEu)) << (16 * i);
                }
                zw[j] = wp | ez;
            }

            // throttle: publishing z_t destroys z_{t-8}; progL>=t-6 certifies.
            if (need >= 0) {
                int g = 0;
                while (plv < want && g < SPIN_LIM) { plv = aload32(&progL[sgate]); ++g; }
            }
            {
                u64* dz = hexZ + ((size_t)nb * 4 + r) * 2048;
                astore(&dz[z0], zw[0]);
                astore(&dz[z0 + 64], zw[1]);
            }
            if (tt + 1 < Tc) {
                u64* srcn = hex0 + ((size_t)((t + 1) & 7) * 4 + r) * 2048;
#pragma unroll
                for (int k = 0; k < 8; ++k) vv[k] = aload(&srcn[wbase + k]);
            }
            __syncthreads();   // protect sH0 rewrite next iteration
        }
        return;
    }

    // ========== L0 / L1REC: 256-col WG, K-split MFMA around exchange ==========
    const int s = b >> 3;                 // col-half: cols [s*256, +256)
    const int c = b & 7;
    const int role = c >> 2;              // 0 = L0, 1 = L1REC
    const int r = c & 3;
    const int rows0 = r * 16;
    const int c0w = s * 256 + w * 64;     // wave's 64 out-cols
    const f16* Wrec = role ? Whh1 : Whh0;
    f16* hcar = role ? hc1 : hc0;
    u64* hexOwn = role ? hex1 : hex0;
    f16* WL = big;

    // j-blocks 0,1 in registers (cols c0w+0..31).
    half8 Bf[2][16];
#pragma unroll
    for (int j = 0; j < 2; ++j)
#pragma unroll
        for (int kc = 0; kc < 16; ++kc)
            Bf[j][kc] = *(const half8*)(Wrec + (size_t)(c0w + j * 16 + lr) * H_DIM
                                        + kc * 32 + quad * 8);

    // WL: 128 LDS cols; cl -> global col s*256 + (cl>>5)*64 + 32 + (cl&31).
    {
        for (int it = 0; it < 32; ++it) {
            int idx = tid * 32 + it;
            int cl = idx >> 6, g = idx & 63;
            int gc = s * 256 + (cl >> 5) * 64 + 32 + (cl & 31);
            *(uint4*)&WL[cl * 512 + ((g ^ (cl & 7)) * 8)] =
                *(const uint4*)(Wrec + (size_t)gc * H_DIM + g * 8);
        }
    }

    // stage <- carry (all 512 cols) on chunk continuation.
    if (t0 > 0) {
        int row = tid >> 4, g0 = (tid & 15) * 4;
#pragma unroll
        for (int gq = 0; gq < 4; ++gq) {
            int g = g0 + gq;
            *(uint4*)&stage[row * 512 + ((g ^ (row & 7)) * 8)] =
                *(const uint4*)(hcar + (size_t)(rows0 + row) * H_DIM + g * 8);
        }
    }

    const int cl2 = w * 32 + lr, cl3 = cl2 + 16;      // WL cols (j=2,3)
    const int z0 = (c0w + lr) * 4 + quad;             // own publish base
    const int wr0 = (1 - s) * 1024 + tid * 4;         // remote words [wr0,+4)

    u64 sv[4];                             // in-flight remote words (t-1)
    u64 vvz[4];                            // L1REC in-flight z words (t)
    if (role) {
        u64* zb = hexZ + ((size_t)(t0 & 7) * 4 + r) * 2048;
#pragma unroll
        for (int k = 0; k < 4; ++k) vvz[k] = aload(&zb[z0 + k * 64]);
    }
    f16 pvh[4][4];                         // L0 pre_t (pipelined)
    if (!role) {
#pragma unroll
        for (int j = 0; j < 4; ++j)
#pragma unroll
            for (int i = 0; i < 4; ++i)
                pvh[j][i] = pre0[((size_t)(rows0 + quad * 4 + i) * Tc + 0) * H_DIM
                                 + c0w + j * 16 + lr];
    }

// 4-MFMA group at compile-time kc (Bf static index; WL/stage runtime addr ok).
#define MF4(KC) do {                                                          \
    half8 _a = *(const half8*)&stage[lr * 512 +                               \
                                     ((((KC) * 4 + quad) ^ (lr & 7)) * 8)];   \
    acc[0] = __builtin_amdgcn_mfma_f32_16x16x32_f16(_a, Bf[0][(KC)], acc[0], 0, 0, 0); \
    acc[1] = __builtin_amdgcn_mfma_f32_16x16x32_f16(_a, Bf[1][(KC)], acc[1], 0, 0, 0); \
    half8 _b2 = *(const half8*)&WL[cl2 * 512 + ((((KC) * 4 + quad) ^ (cl2 & 7)) * 8)]; \
    half8 _b3 = *(const half8*)&WL[cl3 * 512 + ((((KC) * 4 + quad) ^ (cl3 & 7)) * 8)]; \
    acc[2] = __builtin_amdgcn_mfma_f32_16x16x32_f16(_a, _b2, acc[2], 0, 0, 0); \
    acc[3] = __builtin_amdgcn_mfma_f32_16x16x32_f16(_a, _b3, acc[3], 0, 0, 0); \
} while (0)
#define DP_LO() do { MF4(0); MF4(1); MF4(2); MF4(3); MF4(4); MF4(5); MF4(6); MF4(7); } while (0)
#define DP_HI() do { MF4(8); MF4(9); MF4(10); MF4(11); MF4(12); MF4(13); MF4(14); MF4(15); } while (0)

    for (int tt = 0; tt < Tc; ++tt) {
        const int t = t0 + tt;
        const u64 em = tagmask(t);
        const int nbOwn = role ? (t & 1) : (t & 7);
        const int need = t - LAG;
        const u32 want = (u32)(need + 1);

        __syncthreads();   // B1: own h_{t-1} stage writes (prev [E]) visible

        // L1REC: report consumed z_{t-1} (all waves past E of t-1).
        if (role && tid == 0) astore32(&progL[r * 2 + s], (u32)t);

        u32 ppv = 0xffffffffu;
        if (!role && need >= 0 && lane < 4)
            ppv = aload32(&progP[r * 4 + lane]);       // early poll

        float4v acc[4] = {{0.f,0.f,0.f,0.f},{0.f,0.f,0.f,0.f},
                          {0.f,0.f,0.f,0.f},{0.f,0.f,0.f,0.f}};

        // [D1] MFMA over OWN K-half (cols this WG computed; no RT needed).
        if (t > 0) { if (s == 0) DP_LO(); else DP_HI(); }

        // [A] validate remote sibling words of t-1 -> scatter to stage.
        if (tt > 0) {
            u64* src = hexOwn + ((size_t)(role ? ((t - 1) & 1) : ((t - 1) & 7)) * 4 + r) * 2048;
            const u64 emp = tagmask(t - 1);
            int pend = 0;
#pragma unroll
            for (int k = 0; k < 4; ++k)
                if ((sv[k] & SGN) != emp) pend |= 1 << k;
            int guard = 0;
            while (pend && guard < SPIN_LIM) {
#pragma unroll
                for (int k = 0; k < 4; ++k)
                    if (pend & (1 << k)) sv[k] = aload(&src[wr0 + k]);
#pragma unroll
                for (int k = 0; k < 4; ++k)
                    if ((pend & (1 << k)) && ((sv[k] & SGN) == emp))
                        pend &= ~(1 << k);
                ++guard;
            }
#pragma unroll
            for (int k = 0; k < 4; ++k)
                scat_store(stage, wr0 + k, sv[k] & VMASK);
        }
        __syncthreads();   // B2: remote scatters visible

        // [D2] MFMA over REMOTE K-half.
        if (t > 0) { if (s == 0) DP_HI(); else DP_LO(); }

        // L1REC: validate z_t (prefetched; PROJ leads -> usually hit).
        if (role) {
            u64* zb = hexZ + ((size_t)(t & 7) * 4 + r) * 2048;
            const u64 ez = ztag(t);
            int pend = 0;
#pragma unroll
            for (int k = 0; k < 4; ++k)
                if ((vvz[k] & ZMASK) != ez) pend |= 1 << k;
            int guard = 0;
            while (pend && guard < SPIN_LIM) {
#pragma unroll
                for (int k = 0; k < 4; ++k)
                    if (pend & (1 << k)) vvz[k] = aload(&zb[z0 + k * 64]);
#pragma unroll
                for (int k = 0; k < 4; ++k)
                    if ((pend & (1 << k)) && ((vvz[k] & ZMASK) == ez))
                        pend &= ~(1 << k);
                ++guard;
            }
        }

        // [E] h_t = relu(acc + pv): publish first, then stage-own, prefetch.
        f16 hv[4][4];
        u64 pw[4];
#pragma unroll
        for (int j = 0; j < 4; ++j) {
            u64 wp = 0;
#pragma unroll
            for (int i = 0; i < 4; ++i) {
                float pvv;
                if (role) pvv = f16u((u16)((vvz[j] >> (16 * i)) & 0xFFFEu));
                else      pvv = (float)pvh[j][i];
                float hval = fmaxf(acc[j][i] + pvv, 0.f);
                hv[j][i] = (f16)hval;
                union { f16 h; u16 u; } cu2; cu2.h = hv[j][i];
                wp |= ((u64)cu2.u) << (16 * i);
            }
            pw[j] = wp | em;
        }
        // L0 throttle (hex0 ring reuse vs PROJ): resolve just before publish.
        if (!role && need >= 0) {
            bool ok = __all((lane < 4) ? (ppv >= want) : 1);
            int g = 0;
            while (!ok && g < SPIN_LIM) {
                if (lane < 4) ppv = aload32(&progP[r * 4 + lane]);
                ok = __all((lane < 4) ? (ppv >= want) : 1);
                ++g;
            }
        }
        {
            u64* dst = hexOwn + ((size_t)nbOwn * 4 + r) * 2048;
#pragma unroll
            for (int j = 0; j < 4; ++j) astore(&dst[z0 + j * 64], pw[j]);
        }
        // stage own cols (h_t) -- disjoint from [D2]'s remote-col reads.
#pragma unroll
        for (int j = 0; j < 4; ++j)
#pragma unroll
            for (int i = 0; i < 4; ++i) {
                int row = quad * 4 + i, lc = c0w + j * 16 + lr;
                stage[row * 512 + ((lc >> 3) ^ (row & 7)) * 8 + (lc & 7)] = hv[j][i];
            }
        if (role && h_last && t == T_LEN - 1) {
#pragma unroll
            for (int j = 0; j < 4; ++j)
#pragma unroll
                for (int i = 0; i < 4; ++i)
                    h_last[(size_t)(rows0 + quad * 4 + i) * H_DIM + c0w + j * 16 + lr] =
                        (float)hv[j][i];
        }
        if (tt == Tc - 1) {
#pragma unroll
            for (int j = 0; j < 4; ++j)
#pragma unroll
                for (int i = 0; i < 4; ++i)
                    hcar[(size_t)(rows0 + quad * 4 + i) * H_DIM + c0w + j * 16 + lr] =
                        hv[j][i];
        }
        // issue remote sibling loads for step t.
        {
            u64* src = hexOwn + ((size_t)nbOwn * 4 + r) * 2048;
#pragma unroll
            for (int k = 0; k < 4; ++k) sv[k] = aload(&src[wr0 + k]);
        }
        // prefetch next input.
        if (tt + 1 < Tc) {
            if (!role) {
#pragma unroll
                for (int j = 0; j < 4; ++j)
#pragma unroll
                    for (int i = 0; i < 4; ++i)
                        pvh[j][i] = pre0[((size_t)(rows0 + quad * 4 + i) * Tc + tt + 1)
                                         * H_DIM + c0w + j * 16 + lr];
            } else {
                u64* zb = hexZ + ((size_t)((t + 1) & 7) * 4 + r) * 2048;
#pragma unroll
                for (int k = 0; k < 4; ++k) vvz[k] = aload(&zb[z0 + k * 64]);
            }
        }
    }
#undef MF4
#undef DP_LO
#undef DP_HI
}

// --------------------------- final FC --------------------------------------
__global__ void fc_kernel(const float* __restrict__ hlast, const f16* __restrict__ fcw,
                          const float* __restrict__ fcb, void* __restrict__ out,
                          const int* __restrict__ dtf) {
    int b = blockIdx.x, c = threadIdx.x;
    const float* hrow = hlast + b * H_DIM;
    const f16* wrow = fcw + (size_t)c * H_DIM;
    float s = fcb[c];
    for (int h0 = 0; h0 < H_DIM; h0 += 8) {
        half8 w = *(const half8*)(wrow + h0);
#pragma unroll
        for (int j = 0; j < 8; ++j) s += hrow[h0 + j] * (float)w[j];
    }
    if (*dtf) ((float*)out)[b * 128 + c] = s;
    else      ((u16*)out)[b * 128 + c] = f2bf(s);
}

// --------------------------- launch ----------------------------------------
extern "C" void kernel_launch(void* const* d_in, const int* in_sizes, int n_in,
                              void* d_out, int out_size, void* d_ws, size_t ws_size,
                              hipStream_t stream)
{
    const void* x     = d_in[0];
    const void* W_ih0 = d_in[1];
    const void* W_hh0 = d_in[2];
    const void* b_ih0 = d_in[3];
    const void* b_hh0 = d_in[4];
    const void* W_ih1 = d_in[5];
    const void* W_hh1 = d_in[6];
    const void* b_ih1 = d_in[7];
    const void* b_hh1 = d_in[8];
    const void* fc_w  = d_in[9];
    const void* fc_b  = d_in[10];

    char* ws = (char*)d_ws;
    int*   dtf   = (int*)(ws + 0);            //     64 B
    float* bias0 = (float*)(ws + 4096);       //   2048 B
    float* bias1 = (float*)(ws + 6144);       //   2048 B
    float* fcbf  = (float*)(ws + 8192);       //    512 B
    u32*   progP = (u32*)(ws + 12288);        //    256 B
    u32*   progL = (u32*)(ws + 12544);        //    256 B
    float* hlast = (float*)(ws + 16384);      // 131072 B
    f16*   hc0   = (f16*)(ws + 147456);       //  65536 B
    f16*   hc1   = (f16*)(ws + 212992);       //  65536 B
    u64*   hex0  = (u64*)(ws + 278528);       // 524288 B [8][4][2048]
    u64*   hex1  = (u64*)(ws + 802816);       // 131072 B [2][4][2048]
    u64*   hexZ  = (u64*)(ws + 933888);       // 524288 B [8][4][2048]
    f16*   Wih0f = (f16*)(ws + 1458176);      // 262144 B
    f16*   Whh0f = (f16*)(ws + 1720320);      // 524288 B
    f16*   Wih1f = (f16*)(ws + 2244608);      // 524288 B
    f16*   Whh1f = (f16*)(ws + 2768896);      // 524288 B
    f16*   fcwf  = (f16*)(ws + 3293184);      // 131072 B (ends 3424256 < 4MB)

    const size_t misc = 4u << 20;
    int Tc = 128;
    {
        auto need = [&](int tc) {
            return misc + (size_t)B_SZ * (size_t)tc * H_DIM * 2;
        };
        if (ws_size >= need(2048)) Tc = 2048;
        else if (ws_size >= need(1024)) Tc = 1024;
        else if (ws_size >= need(512)) Tc = 512;
        else if (ws_size >= need(256)) Tc = 256;
        else Tc = 128;
    }
    int lgTc = 31 - __builtin_clz((unsigned)Tc);
    f16* bufA = (f16*)(ws + misc);

    detect_kernel<<<dim3(1), dim3(64), 0, stream>>>((const u16*)x, dtf, progP, progL);
    initz_kernel<<<dim3(256), dim3(256), 0, stream>>>(hexZ);
    cvt_w_kernel<<<dim3(512), dim3(256), 0, stream>>>(W_ih0, Wih0f, H_DIM * 256, dtf);
    cvt_w_kernel<<<dim3(1024), dim3(256), 0, stream>>>(W_hh0, Whh0f, H_DIM * H_DIM, dtf);
    cvt_w_kernel<<<dim3(1024), dim3(256), 0, stream>>>(W_ih1, Wih1f, H_DIM * H_DIM, dtf);
    cvt_w_kernel<<<dim3(1024), dim3(256), 0, stream>>>(W_hh1, Whh1f, H_DIM * H_DIM, dtf);
    cvt_w_kernel<<<dim3(256), dim3(256), 0, stream>>>(fc_w, fcwf, 128 * H_DIM, dtf);
    bias_kernel<<<dim3(2), dim3(256), 0, stream>>>(b_ih0, b_hh0, bias0, dtf);
    bias_kernel<<<dim3(2), dim3(256), 0, stream>>>(b_ih1, b_hh1, bias1, dtf);
    fcb_kernel<<<dim3(1), dim3(128), 0, stream>>>(fc_b, fcbf, dtf);

    const int NC = T_LEN / Tc;
    const int mblocks = B_SZ * Tc / 64;
    for (int c = 0; c < NC; ++c) {
        const int t0 = c * Tc;
        gemm_tiled<1><<<dim3(mblocks, 8), 256, 0, stream>>>(
            x, Wih0f, bias0, bufA, lgTc, t0, 256, dtf);
        rnn_scan3<<<dim3(32), dim3(256), 0, stream>>>(
            bufA, Whh0f, Wih1f, Whh1f, bias1, hex0, hex1, hexZ, hc0, hc1,
            progP, progL, t0, Tc, hlast);
    }
    fc_kernel<<<dim3(B_SZ), dim3(128), 0, stream>>>(hlast, fcwf, fcbf, d_out, dtf);
}